// Round 11
// baseline (490.518 us; speedup 1.0000x reference)
//
#include <hip/hip_runtime.h>
#include <cmath>

#define N_NODES 16384
#define N_EDGES 98304
#define N_CAND  1024

typedef __bf16 bf16x8 __attribute__((ext_vector_type(8)));
typedef short  s16x8  __attribute__((ext_vector_type(8)));
typedef float  f32x4  __attribute__((ext_vector_type(4)));
typedef unsigned short u16x4 __attribute__((ext_vector_type(4)));
typedef unsigned short u16x8 __attribute__((ext_vector_type(8)));

__device__ __forceinline__ unsigned short f2bf(float x) {
    unsigned u = __float_as_uint(x);
    return (unsigned short)((u + 0x7fffu + ((u >> 16) & 1u)) >> 16);
}
__device__ __forceinline__ float bf2f(unsigned short b) {
    return __uint_as_float((unsigned)b << 16);
}

#define GLL(gp, lp) __builtin_amdgcn_global_load_lds(                          \
    (const __attribute__((address_space(1))) unsigned int*)(const void*)(gp),  \
    (__attribute__((address_space(3))) unsigned int*)(void*)(lp), 16, 0, 0)

// ---------------------------------------------------------------------------
// CSR build: hist -> single-dispatch scan -> scatter
// ---------------------------------------------------------------------------
__global__ __launch_bounds__(256) void k_hist(const int* __restrict__ tgt,
                                              int* __restrict__ deg) {
    int e = blockIdx.x * 256 + threadIdx.x;
    if (e < N_EDGES) atomicAdd(&deg[tgt[e]], 1);
}

__global__ __launch_bounds__(256) void k_scan_all(const int* __restrict__ deg,
                                                  int* __restrict__ off,
                                                  int* __restrict__ cursor) {
    __shared__ int ts[256];
    int tid = threadIdx.x;
    const int4* d4 = (const int4*)(deg + tid * 64);
    int s = 0;
    #pragma unroll
    for (int i = 0; i < 16; ++i) {
        int4 v = d4[i];
        s += v.x + v.y + v.z + v.w;
    }
    ts[tid] = s;
    __syncthreads();
    for (int o = 1; o < 256; o <<= 1) {
        int t = (tid >= o) ? ts[tid - o] : 0;
        __syncthreads();
        ts[tid] += t;
        __syncthreads();
    }
    int run = ts[tid] - s;
    int4* o4 = (int4*)(off + tid * 64);
    int4* c4 = (int4*)(cursor + tid * 64);
    #pragma unroll
    for (int i = 0; i < 16; ++i) {
        int4 v = d4[i];
        int4 ov;
        ov.x = run; run += v.x;
        ov.y = run; run += v.y;
        ov.z = run; run += v.z;
        ov.w = run; run += v.w;
        o4[i] = ov;
        c4[i] = ov;
    }
    if (tid == 255) off[N_NODES] = run;
}

__global__ __launch_bounds__(256) void k_scatter(const int* __restrict__ ei,
                                                 int* __restrict__ cursor,
                                                 int* __restrict__ csrc) {
    int e = blockIdx.x * 256 + threadIdx.x;
    if (e < N_EDGES) {
        int s = ei[e];
        int t = ei[N_EDGES + e];
        int pos = atomicAdd(&cursor[t], 1);
        csrc[pos] = s;
    }
}

// ---------------------------------------------------------------------------
// Layer 0 scores only (proj recomputed in registers)
// ---------------------------------------------------------------------------
__global__ __launch_bounds__(256) void k_l0s(const float* __restrict__ fea,
                                             const float* __restrict__ W0,
                                             const float* __restrict__ as,
                                             const float* __restrict__ at,
                                             float* __restrict__ ssrc,
                                             float* __restrict__ stgt) {
    int n = blockIdx.x, tid = threadIdx.x;
    float f0 = fea[n * 3 + 0], f1 = fea[n * 3 + 1], f2 = fea[n * 3 + 2];
    int c1 = tid, c2 = tid + 256;
    float p1 = f0 * W0[c1] + f1 * W0[512 + c1] + f2 * W0[1024 + c1];
    float p2 = f0 * W0[c2] + f1 * W0[512 + c2] + f2 * W0[1024 + c2];
    float vs1 = p1 * as[c1], vt1 = p1 * at[c1];
    float vs2 = p2 * as[c2], vt2 = p2 * at[c2];
    #pragma unroll
    for (int o = 32; o; o >>= 1) {
        vs1 += __shfl_xor(vs1, o); vt1 += __shfl_xor(vt1, o);
        vs2 += __shfl_xor(vs2, o); vt2 += __shfl_xor(vt2, o);
    }
    int lane = tid & 63, w = tid >> 6;
    if (lane == 0) {
        ssrc[n * 8 + w]     = vs1;  stgt[n * 8 + w]     = vt1;
        ssrc[n * 8 + w + 4] = vs2;  stgt[n * 8 + w + 4] = vt2;
    }
}

// ---------------------------------------------------------------------------
// Weight pack (both layers in one dispatch)
// ---------------------------------------------------------------------------
__device__ __forceinline__ void pack_slot(const float* __restrict__ src0,
                                          const float* __restrict__ src1,
                                          int splitN, int NTOT, int NKB, int s,
                                          unsigned short* __restrict__ hi,
                                          unsigned short* __restrict__ lo) {
    int nb = s / (NKB * 512);
    int rem = s - nb * (NKB * 512);
    int kb = rem >> 9;
    int sl = rem & 511;
    int c = sl >> 7, n = sl & 127;
    int col = nb * 128 + n;
    const float* src;
    int cc, stride;
    if (col < splitN) { src = src0; cc = col; stride = splitN; }
    else              { src = src1; cc = col - splitN; stride = NTOT - splitN; }
    int k0 = kb * 32 + c * 8;
    s16x8 hv, lv;
    #pragma unroll
    for (int j = 0; j < 8; ++j) {
        float w = src[(size_t)(k0 + j) * stride + cc];
        unsigned short h = f2bf(w);
        hv[j] = (short)h;
        lv[j] = (short)f2bf(w - bf2f(h));
    }
    *(s16x8*)(hi + (size_t)s * 8) = hv;
    *(s16x8*)(lo + (size_t)s * 8) = lv;
}

__global__ __launch_bounds__(256) void k_pack_all(
    const float* __restrict__ W1, const float* __restrict__ sk1,
    unsigned short* __restrict__ pw1h, unsigned short* __restrict__ pw1l,
    const float* __restrict__ W2, const float* __restrict__ sk2,
    unsigned short* __restrict__ pw2h, unsigned short* __restrict__ pw2l) {
    int s = blockIdx.x * 256 + threadIdx.x;
    if (s < 131072) {
        pack_slot(W1, sk1, 1024, 2048, 16, s, pw1h, pw1l);
    } else {
        int s2 = s - 131072;
        if (s2 < 16384) pack_slot(W2, sk2, 64, 128, 32, s2, pw2h, pw2l);
    }
}

// ---------------------------------------------------------------------------
// bf16x3-split MFMA GEMM (verified round-5 form).
// ---------------------------------------------------------------------------
template <int F, int NTOT, int KS>
__global__ __launch_bounds__(256, 2) void k_gemm_mfma(
    const unsigned short* __restrict__ Xhi, const unsigned short* __restrict__ Xlo,
    const unsigned short* __restrict__ Wph, const unsigned short* __restrict__ Wpl,
    float* __restrict__ out0, float* __restrict__ out1, int splitN) {
    constexpr int NKB = F / 32;
    static_assert(KS == 1 || NTOT == 128, "split-K assumes single col-block");
    __shared__ unsigned short lds[2 * 16384];
    const int tid = threadIdx.x;
    const int bm  = blockIdx.y * 128;
    const int nb  = blockIdx.x;

    const int sA0 = tid, sA1 = tid + 256;
    const int rA0 = sA0 >> 2, rA1 = sA1 >> 2;
    const int cA0 = (sA0 & 3) ^ ((rA0 >> 1) & 3);
    const int cA1 = (sA1 & 3) ^ ((rA1 >> 1) & 3);
    const unsigned short* gAh0 = Xhi + (size_t)(bm + rA0) * F + cA0 * 8;
    const unsigned short* gAh1 = Xhi + (size_t)(bm + rA1) * F + cA1 * 8;
    const unsigned short* gAl0 = Xlo + (size_t)(bm + rA0) * F + cA0 * 8;
    const unsigned short* gAl1 = Xlo + (size_t)(bm + rA1) * F + cA1 * 8;
    const unsigned short* gBh  = Wph + (KS == 1 ? (size_t)nb * NKB * 4096 : 0);
    const unsigned short* gBl  = Wpl + (KS == 1 ? (size_t)nb * NKB * 4096 : 0);

    const int wave = tid >> 6, lane = tid & 63;
    const int wm = wave >> 1, wn = wave & 1;
    const int l15 = lane & 15, lc = lane >> 4;

    int offA[4], offB[4];
    #pragma unroll
    for (int mi = 0; mi < 4; ++mi) {
        int row = wm * 64 + mi * 16 + l15;
        int chp = lc ^ ((row >> 1) & 3);
        offA[mi] = row * 32 + chp * 8;
    }
    #pragma unroll
    for (int ni = 0; ni < 4; ++ni) {
        int n = wn * 64 + ni * 16 + l15;
        offB[ni] = 8192 + (lc * 128 + n) * 8;
    }

    f32x4 acc[4][4];
    #pragma unroll
    for (int i = 0; i < 4; ++i)
        #pragma unroll
        for (int j = 0; j < 4; ++j)
            acc[i][j] = (f32x4){0.f, 0.f, 0.f, 0.f};

    auto stage = [&](int kb, int buf) {
        unsigned short* l = &lds[buf * 16384];
        const size_t ka  = (size_t)kb * 32;
        const size_t kbb = (size_t)kb * 4096;
        GLL(gAh0 + ka, l + sA0 * 8);
        GLL(gAh1 + ka, l + sA1 * 8);
        GLL(gAl0 + ka, l + 4096 + sA0 * 8);
        GLL(gAl1 + ka, l + 4096 + sA1 * 8);
        GLL(gBh + kbb + sA0 * 8, l + 8192 + sA0 * 8);
        GLL(gBh + kbb + sA1 * 8, l + 8192 + sA1 * 8);
        GLL(gBl + kbb + sA0 * 8, l + 12288 + sA0 * 8);
        GLL(gBl + kbb + sA1 * 8, l + 12288 + sA1 * 8);
    };

    const int kb0 = (KS > 1) ? nb * (NKB / KS) : 0;
    const int kbN = (KS > 1) ? (NKB / KS) : NKB;

    stage(kb0, 0);
    __syncthreads();

    for (int ki = 0; ki < kbN; ++ki) {
        const int buf = ki & 1;
        if (ki + 1 < kbN) stage(kb0 + ki + 1, buf ^ 1);
        const unsigned short* l = &lds[buf * 16384];
        bf16x8 ah[4], al[4], bh[4], bl[4];
        #pragma unroll
        for (int mi = 0; mi < 4; ++mi) {
            ah[mi] = *(const bf16x8*)(l + offA[mi]);
            al[mi] = *(const bf16x8*)(l + 4096 + offA[mi]);
        }
        #pragma unroll
        for (int ni = 0; ni < 4; ++ni) {
            bh[ni] = *(const bf16x8*)(l + offB[ni]);
            bl[ni] = *(const bf16x8*)(l + 4096 + offB[ni]);
        }
        #pragma unroll
        for (int mi = 0; mi < 4; ++mi)
            #pragma unroll
            for (int ni = 0; ni < 4; ++ni) {
                acc[mi][ni] = __builtin_amdgcn_mfma_f32_16x16x32_bf16(ah[mi], bh[ni], acc[mi][ni], 0, 0, 0);
                acc[mi][ni] = __builtin_amdgcn_mfma_f32_16x16x32_bf16(ah[mi], bl[ni], acc[mi][ni], 0, 0, 0);
                acc[mi][ni] = __builtin_amdgcn_mfma_f32_16x16x32_bf16(al[mi], bh[ni], acc[mi][ni], 0, 0, 0);
            }
        __syncthreads();
    }

    if constexpr (KS > 1) {
        #pragma unroll
        for (int ni = 0; ni < 4; ++ni) {
            int col = wn * 64 + ni * 16 + l15;
            #pragma unroll
            for (int mi = 0; mi < 4; ++mi) {
                int row0 = bm + wm * 64 + mi * 16 + lc * 4;
                #pragma unroll
                for (int r = 0; r < 4; ++r)
                    out0[((size_t)nb * N_NODES + row0 + r) * NTOT + col] = acc[mi][ni][r];
            }
        }
    } else {
        #pragma unroll
        for (int ni = 0; ni < 4; ++ni) {
            int col = nb * 128 + wn * 64 + ni * 16 + l15;
            float* o;
            int cc, stride;
            if (col < splitN) { o = out0; cc = col; stride = splitN; }
            else              { o = out1; cc = col - splitN; stride = NTOT - splitN; }
            #pragma unroll
            for (int mi = 0; mi < 4; ++mi) {
                int row0 = bm + wm * 64 + mi * 16 + lc * 4;
                #pragma unroll
                for (int r = 0; r < 4; ++r)
                    o[(size_t)(row0 + r) * stride + cc] = acc[mi][ni][r];
            }
        }
    }
}

// ---------------------------------------------------------------------------
// Attention scores (layer 1) — P-based, fully coalesced.
// ---------------------------------------------------------------------------
template <int H, int FO>
__global__ __launch_bounds__(256) void k_scores(const float* __restrict__ P,
                                                const float* __restrict__ asrc,
                                                const float* __restrict__ atgt,
                                                float* __restrict__ ssrc,
                                                float* __restrict__ stgt) {
    constexpr int K = H * FO;
    int gid  = blockIdx.x * 4 + (threadIdx.x >> 6);
    int lane = threadIdx.x & 63;
    int n = gid / H, h = gid - n * H;
    if (n >= N_NODES) return;
    float vs = 0.f, vt = 0.f;
    #pragma unroll
    for (int q = 0; q < FO / 64; ++q) {
        int f = lane + q * 64;
        float p = P[(size_t)n * K + h * FO + f];
        vs += p * asrc[h * FO + f];
        vt += p * atgt[h * FO + f];
    }
    #pragma unroll
    for (int o = 32; o; o >>= 1) {
        vs += __shfl_xor(vs, o);
        vt += __shfl_xor(vt, o);
    }
    if (lane == 0) {
        ssrc[n * H + h] = vs;
        stgt[n * H + h] = vt;
    }
}

// ---------------------------------------------------------------------------
// Split-K reduce + layer-2 scores, fused. 16 nodes per block.
// ---------------------------------------------------------------------------
__global__ __launch_bounds__(256) void k_red2s(const float* __restrict__ part,
                                               const float* __restrict__ as2,
                                               const float* __restrict__ at2,
                                               float* __restrict__ P2,
                                               float* __restrict__ S2,
                                               float* __restrict__ ssrc,
                                               float* __restrict__ stgt) {
    int tid = threadIdx.x;
    int node = blockIdx.x * 16 + (tid >> 4);
    int cg = tid & 15;
    int c0 = cg * 8;
    const float* p0 = part + (size_t)node * 128 + c0;
    float v[8];
    {
        float4 a = *(const float4*)(p0);
        float4 b = *(const float4*)(p0 + 4);
        v[0]=a.x; v[1]=a.y; v[2]=a.z; v[3]=a.w; v[4]=b.x; v[5]=b.y; v[6]=b.z; v[7]=b.w;
    }
    #pragma unroll
    for (int ks = 1; ks < 4; ++ks) {
        const float* pk = p0 + (size_t)ks * N_NODES * 128;
        float4 a = *(const float4*)(pk);
        float4 b = *(const float4*)(pk + 4);
        v[0]+=a.x; v[1]+=a.y; v[2]+=a.z; v[3]+=a.w; v[4]+=b.x; v[5]+=b.y; v[6]+=b.z; v[7]+=b.w;
    }
    if (cg < 8) {
        float s = 0.f, t = 0.f;
        #pragma unroll
        for (int j = 0; j < 8; ++j) {
            s += v[j] * as2[c0 + j];
            t += v[j] * at2[c0 + j];
        }
        #pragma unroll
        for (int o = 1; o < 8; o <<= 1) { s += __shfl_xor(s, o); t += __shfl_xor(t, o); }
        float* d = P2 + (size_t)node * 64 + c0;
        *(float4*)(d)     = make_float4(v[0], v[1], v[2], v[3]);
        *(float4*)(d + 4) = make_float4(v[4], v[5], v[6], v[7]);
        if (cg == 0) { ssrc[node] = s; stgt[node] = t; }
    } else {
        float* d = S2 + (size_t)node * 64 + (c0 - 64);
        *(float4*)(d)     = make_float4(v[0], v[1], v[2], v[3]);
        *(float4*)(d + 4) = make_float4(v[4], v[5], v[6], v[7]);
    }
}

// ---------------------------------------------------------------------------
// Wave-per-node layer-0 attention: zero barriers, zero LDS.
// Lane = e*8 + h over edge chunks of 8; proj/skip from fea on the fly.
// ---------------------------------------------------------------------------
__global__ __launch_bounds__(256) void k_attn0_w(
    const float* __restrict__ fea, const float* __restrict__ W0,
    const float* __restrict__ sk0, const float* __restrict__ ssrc,
    const float* __restrict__ stgt, const int* __restrict__ off,
    const int* __restrict__ csrc, const float* __restrict__ bias,
    unsigned short* __restrict__ ohi, unsigned short* __restrict__ olo) {
    constexpr int H = 8, K = 512, EPC = 8;
    int wv = threadIdx.x >> 6, lane = threadIdx.x & 63;
    int n = blockIdx.x * 4 + wv;
    int he = lane >> 3, hh = lane & 7;
    int c0 = lane * 8;

    float w0r[8], w1r[8], w2r[8];
    #pragma unroll
    for (int j = 0; j < 8; ++j) {
        w0r[j] = W0[c0 + j];
        w1r[j] = W0[512 + c0 + j];
        w2r[j] = W0[1024 + c0 + j];
    }
    float st_h = stgt[n * H + hh];
    int d0 = off[n], deg = off[n + 1] - d0;

    // pass 1: per-head online max + denom (shfl tree over e-dim)
    float m = -INFINITY, d = 0.f;
    for (int base = 0; base < deg; base += EPC) {
        int cnt = min(EPC, deg - base);
        float s = -INFINITY;
        if (he < cnt) {
            int se = csrc[d0 + base + he];
            float v = ssrc[se * H + hh] + st_h;
            s = (v >= 0.f) ? v : 0.2f * v;
        }
        float cm = s;
        #pragma unroll
        for (int o = H; o < 64; o <<= 1) cm = fmaxf(cm, __shfl_xor(cm, o));
        float nm = fmaxf(m, cm);
        float pe = (he < cnt) ? expf(s - nm) : 0.f;
        #pragma unroll
        for (int o = H; o < 64; o <<= 1) pe += __shfl_xor(pe, o);
        d = ((m == -INFINITY) ? 0.f : d * expf(m - nm)) + pe;
        m = nm;
    }
    float dinv = 1.f / (d + 1e-16f);

    // pass 2: alpha recompute + aggregate
    float acc[8] = {0.f, 0.f, 0.f, 0.f, 0.f, 0.f, 0.f, 0.f};
    for (int base = 0; base < deg; base += EPC) {
        int cnt = min(EPC, deg - base);
        int msrc = 0;
        float al = 0.f;
        if (he < cnt) {
            msrc = csrc[d0 + base + he];
            float v = ssrc[msrc * H + hh] + st_h;
            v = (v >= 0.f) ? v : 0.2f * v;
            al = expf(v - m) * dinv;
        }
        for (int e = 0; e < cnt; ++e) {
            int se = __shfl(msrc, e * 8);
            float f0 = fea[se * 3], f1 = fea[se * 3 + 1], f2 = fea[se * 3 + 2];
            float a = __shfl(al, e * 8 + (lane >> 3));
            #pragma unroll
            for (int j = 0; j < 8; ++j)
                acc[j] += (f0 * w0r[j] + f1 * w1r[j] + f2 * w2r[j]) * a;
        }
    }

    float f0 = fea[n * 3], f1 = fea[n * 3 + 1], f2 = fea[n * 3 + 2];
    u16x8 hv, lv;
    #pragma unroll
    for (int j = 0; j < 8; ++j) {
        float r = acc[j] + f0 * sk0[c0 + j] + f1 * sk0[512 + c0 + j]
                + f2 * sk0[1024 + c0 + j] + bias[c0 + j];
        r = (r > 0.f) ? r : expm1f(r);
        unsigned short hb = f2bf(r);
        hv[j] = hb;
        lv[j] = f2bf(r - bf2f(hb));
    }
    *(u16x8*)(ohi + (size_t)n * K + c0) = hv;
    *(u16x8*)(olo + (size_t)n * K + c0) = lv;
}

// ---------------------------------------------------------------------------
// Wave-per-node generic attention (layers 1,2): zero barriers, zero LDS.
// Lane = e*H + h over edge chunks of 64/H; per-edge coalesced P-row gather.
// ---------------------------------------------------------------------------
template <int H, int FO, bool ACT, bool SPLIT, bool CAND>
__global__ __launch_bounds__(256) void k_attn_w(
    const float* __restrict__ P, const float* __restrict__ ssrc,
    const float* __restrict__ stgt, const int* __restrict__ off,
    const int* __restrict__ csrc, const float* __restrict__ bias,
    const float* __restrict__ skipin, float* __restrict__ outf,
    unsigned short* __restrict__ ohi, unsigned short* __restrict__ olo,
    const int* __restrict__ nidx) {
    constexpr int K   = H * FO;
    constexpr int EPC = 64 / H;
    constexpr int NC  = (K + 255) / 256;
    int wv = threadIdx.x >> 6, lane = threadIdx.x & 63;
    int idx = blockIdx.x * 4 + wv;
    int n = CAND ? nidx[idx] : idx;
    int orow = CAND ? idx : n;
    int he = lane / H, hh = lane % H;

    float st_h = stgt[n * H + hh];
    int d0 = off[n], deg = off[n + 1] - d0;

    // pass 1: per-head online max + denom
    float m = -INFINITY, d = 0.f;
    for (int base = 0; base < deg; base += EPC) {
        int cnt = min(EPC, deg - base);
        float s = -INFINITY;
        if (he < cnt) {
            int se = csrc[d0 + base + he];
            float v = ssrc[se * H + hh] + st_h;
            s = (v >= 0.f) ? v : 0.2f * v;
        }
        float cm = s;
        #pragma unroll
        for (int o = H; o < 64; o <<= 1) cm = fmaxf(cm, __shfl_xor(cm, o));
        float nm = fmaxf(m, cm);
        float pe = (he < cnt) ? expf(s - nm) : 0.f;
        #pragma unroll
        for (int o = H; o < 64; o <<= 1) pe += __shfl_xor(pe, o);
        d = ((m == -INFINITY) ? 0.f : d * expf(m - nm)) + pe;
        m = nm;
    }
    float dinv = 1.f / (d + 1e-16f);

    // pass 2: alpha recompute + coalesced per-edge gather
    float4 acc[NC];
    #pragma unroll
    for (int c = 0; c < NC; ++c) acc[c] = make_float4(0.f, 0.f, 0.f, 0.f);

    for (int base = 0; base < deg; base += EPC) {
        int cnt = min(EPC, deg - base);
        int msrc = 0;
        float al = 0.f;
        if (he < cnt) {
            msrc = csrc[d0 + base + he];
            float v = ssrc[msrc * H + hh] + st_h;
            v = (v >= 0.f) ? v : 0.2f * v;
            al = expf(v - m) * dinv;
        }
        for (int e = 0; e < cnt; ++e) {
            int se = __shfl(msrc, e * H);
            const float* pr = P + (size_t)se * K;
            #pragma unroll
            for (int c = 0; c < NC; ++c) {
                int col = c * 256 + lane * 4;
                if (K % 256 == 0 || col < K) {
                    float a = __shfl(al, e * H + col / FO);
                    float4 v = *(const float4*)(pr + col);
                    acc[c].x += v.x * a; acc[c].y += v.y * a;
                    acc[c].z += v.z * a; acc[c].w += v.w * a;
                }
            }
        }
    }

    #pragma unroll
    for (int c = 0; c < NC; ++c) {
        int col = c * 256 + lane * 4;
        if (K % 256 == 0 || col < K) {
            const float4 s4 = *(const float4*)(skipin + (size_t)n * K + col);
            const float4 b4 = *(const float4*)(bias + col);
            float r[4] = {acc[c].x + s4.x + b4.x, acc[c].y + s4.y + b4.y,
                          acc[c].z + s4.z + b4.z, acc[c].w + s4.w + b4.w};
            #pragma unroll
            for (int j = 0; j < 4; ++j)
                if (ACT) r[j] = (r[j] > 0.f) ? r[j] : expm1f(r[j]);
            if constexpr (SPLIT) {
                u16x4 hv, lv;
                #pragma unroll
                for (int j = 0; j < 4; ++j) {
                    unsigned short hb = f2bf(r[j]);
                    hv[j] = hb;
                    lv[j] = f2bf(r[j] - bf2f(hb));
                }
                *(u16x4*)(ohi + (size_t)orow * K + col) = hv;
                *(u16x4*)(olo + (size_t)orow * K + col) = lv;
            } else {
                *(float4*)(outf + (size_t)orow * K + col) =
                    make_float4(r[0], r[1], r[2], r[3]);
            }
        }
    }
}

// ---------------------------------------------------------------------------
// Batched candidate MLP head: 16 candidates per block.
// ---------------------------------------------------------------------------
__global__ __launch_bounds__(256) void k_mlp(const float* __restrict__ X3c,
                                             const int* __restrict__ cid,
                                             const float* __restrict__ W1,
                                             const float* __restrict__ b1,
                                             const float* __restrict__ W2,
                                             const float* __restrict__ b2,
                                             const float* __restrict__ W3,
                                             const float* __restrict__ b3,
                                             float* __restrict__ out) {
    __shared__ float cf[16][64];
    __shared__ float h1s[16][256];
    __shared__ float red[16][4];
    int tid = threadIdx.x;
    int cbase = blockIdx.x * 16;
    for (int i = tid; i < 16 * 64; i += 256)
        cf[i >> 6][i & 63] = X3c[(size_t)cbase * 64 + i];
    __syncthreads();
    float a[16];
    #pragma unroll
    for (int ci = 0; ci < 16; ++ci) a[ci] = b1[tid];
    for (int k = 0; k < 64; ++k) {
        float wv = W1[k * 256 + tid];
        #pragma unroll
        for (int ci = 0; ci < 16; ++ci) a[ci] += cf[ci][k] * wv;
    }
    #pragma unroll
    for (int ci = 0; ci < 16; ++ci) h1s[ci][tid] = tanhf(a[ci]);
    __syncthreads();
    #pragma unroll
    for (int ci = 0; ci < 16; ++ci) a[ci] = b2[tid];
    for (int k = 0; k < 256; ++k) {
        float wv = W2[k * 256 + tid];
        #pragma unroll
        for (int ci = 0; ci < 16; ++ci) a[ci] += h1s[ci][k] * wv;
    }
    float w3 = W3[tid];
    int lane = tid & 63, wv_ = tid >> 6;
    #pragma unroll
    for (int ci = 0; ci < 16; ++ci) {
        float v = tanhf(a[ci]) * w3;
        #pragma unroll
        for (int o = 32; o; o >>= 1) v += __shfl_xor(v, o);
        if (lane == 0) red[ci][wv_] = v;
    }
    __syncthreads();
    if (tid < 16) {
        int c = cbase + tid;
        out[c] = red[tid][0] + red[tid][1] + red[tid][2] + red[tid][3] + b3[0];
        out[N_CAND + c] = (float)cid[c];
    }
}

// ---------------------------------------------------------------------------
extern "C" void kernel_launch(void* const* d_in, const int* in_sizes, int n_in,
                              void* d_out, int out_size, void* d_ws, size_t ws_size,
                              hipStream_t stream) {
    const float* fea  = (const float*)d_in[0];
    const int*   ei   = (const int*)d_in[1];
    const int*   cid  = (const int*)d_in[2];
    const float* W0   = (const float*)d_in[3];
    const float* as0  = (const float*)d_in[4];
    const float* at0  = (const float*)d_in[5];
    const float* b0   = (const float*)d_in[6];
    const float* sk0  = (const float*)d_in[7];
    const float* W1   = (const float*)d_in[8];
    const float* as1  = (const float*)d_in[9];
    const float* at1  = (const float*)d_in[10];
    const float* b1   = (const float*)d_in[11];
    const float* sk1  = (const float*)d_in[12];
    const float* W2   = (const float*)d_in[13];
    const float* as2  = (const float*)d_in[14];
    const float* at2  = (const float*)d_in[15];
    const float* b2   = (const float*)d_in[16];
    const float* sk2  = (const float*)d_in[17];
    const float* mW1  = (const float*)d_in[18];
    const float* mb1  = (const float*)d_in[19];
    const float* mW2  = (const float*)d_in[20];
    const float* mb2  = (const float*)d_in[21];
    const float* mW3  = (const float*)d_in[22];
    const float* mb3  = (const float*)d_in[23];

    char* w = (char*)d_ws;
    auto alloc = [&](size_t bytes) -> void* {
        void* p = (void*)w;
        w += (bytes + 255) & ~(size_t)255;
        return p;
    };
    int*   deg    = (int*)alloc((size_t)N_NODES * 4);
    int*   off    = (int*)alloc((size_t)(N_NODES + 1) * 4);
    int*   cursor = (int*)alloc((size_t)N_NODES * 4);
    int*   csrc   = (int*)alloc((size_t)N_EDGES * 4);
    float* ssrc   = (float*)alloc((size_t)N_NODES * 8 * 4);
    float* stgt   = (float*)alloc((size_t)N_NODES * 8 * 4);
    float* P      = (float*)alloc((size_t)N_NODES * 1024 * 4);   // proj1 -> part
    float* S      = (float*)alloc((size_t)N_NODES * 1024 * 4);   // skip1 -> P2/S2/X3c
    unsigned short* Xs = (unsigned short*)alloc((size_t)N_NODES * 1024 * 4);
    unsigned short* pw1h = (unsigned short*)alloc((size_t)512 * 2048 * 2);
    unsigned short* pw1l = (unsigned short*)alloc((size_t)512 * 2048 * 2);
    unsigned short* pw2h = (unsigned short*)alloc((size_t)1024 * 128 * 2);
    unsigned short* pw2l = (unsigned short*)alloc((size_t)1024 * 128 * 2);

    unsigned short* X1hi = Xs;
    unsigned short* X1lo = Xs + (size_t)N_NODES * 512;
    unsigned short* X2hi = Xs;
    unsigned short* X2lo = Xs + (size_t)N_NODES * 1024;
    float* part = P;                                   // 4 x 16384 x 128 fp32
    float* P2   = S;                                   // proj2 (16384 x 64)
    float* S2   = S + (size_t)N_NODES * 64;            // skip2 (16384 x 64)
    float* X3c  = S + (size_t)2 * N_NODES * 64;        // compact cand out

    // CSR build
    hipMemsetAsync(deg, 0, (size_t)N_NODES * 4, stream);
    k_hist<<<N_EDGES / 256, 256, 0, stream>>>(ei + N_EDGES, deg);
    k_scan_all<<<1, 256, 0, stream>>>(deg, off, cursor);
    k_scatter<<<N_EDGES / 256, 256, 0, stream>>>(ei, cursor, csrc);

    // Weight packing (both layers, one dispatch)
    k_pack_all<<<576, 256, 0, stream>>>(W1, sk1, pw1h, pw1l, W2, sk2, pw2h, pw2l);

    // Layer 0
    k_l0s<<<N_NODES, 256, 0, stream>>>(fea, W0, as0, at0, ssrc, stgt);
    k_attn0_w<<<N_NODES / 4, 256, 0, stream>>>(fea, W0, sk0, ssrc, stgt, off,
                                               csrc, b0, X1hi, X1lo);

    // Layer 1: fused proj+skip GEMM (N=2048), P-based scores, wave attention
    {
        dim3 g(16, N_NODES / 128);
        k_gemm_mfma<512, 2048, 1><<<g, 256, 0, stream>>>(
            X1hi, X1lo, pw1h, pw1l, P, S, 1024);
    }
    k_scores<8, 128><<<N_NODES * 8 / 4, 256, 0, stream>>>(P, as1, at1, ssrc, stgt);
    k_attn_w<8, 128, true, true, false><<<N_NODES / 4, 256, 0, stream>>>(
        P, ssrc, stgt, off, csrc, b1, S, nullptr, X2hi, X2lo, nullptr);

    // Layer 2: split-K=4 GEMM -> fused reduce + scores -> candidate-only attn
    {
        dim3 g(4, N_NODES / 128);
        k_gemm_mfma<1024, 128, 4><<<g, 256, 0, stream>>>(
            X2hi, X2lo, pw2h, pw2l, part, nullptr, 128);
    }
    k_red2s<<<N_NODES / 16, 256, 0, stream>>>(part, as2, at2, P2, S2, ssrc, stgt);
    k_attn_w<1, 64, false, false, true><<<N_CAND / 4, 256, 0, stream>>>(
        P2, ssrc, stgt, off, csrc, b2, S2, X3c, nullptr, nullptr, cid);

    // Batched candidate MLP head
    k_mlp<<<N_CAND / 16, 256, 0, stream>>>(X3c, cid, mW1, mb1, mW2, mb2, mW3, mb3,
                                           (float*)d_out);
}

// Round 12
// 459.593 us; speedup vs baseline: 1.0673x; 1.0673x over previous
//
#include <hip/hip_runtime.h>
#include <cmath>

#define N_NODES 16384
#define N_EDGES 98304
#define N_CAND  1024

typedef __bf16 bf16x8 __attribute__((ext_vector_type(8)));
typedef short  s16x8  __attribute__((ext_vector_type(8)));
typedef float  f32x4  __attribute__((ext_vector_type(4)));
typedef unsigned short u16x2 __attribute__((ext_vector_type(2)));
typedef unsigned short u16x4 __attribute__((ext_vector_type(4)));

__device__ __forceinline__ unsigned short f2bf(float x) {
    unsigned u = __float_as_uint(x);
    return (unsigned short)((u + 0x7fffu + ((u >> 16) & 1u)) >> 16);
}
__device__ __forceinline__ float bf2f(unsigned short b) {
    return __uint_as_float((unsigned)b << 16);
}

#define GLL(gp, lp) __builtin_amdgcn_global_load_lds(                          \
    (const __attribute__((address_space(1))) unsigned int*)(const void*)(gp),  \
    (__attribute__((address_space(3))) unsigned int*)(void*)(lp), 16, 0, 0)

// ---------------------------------------------------------------------------
// CSR build: hist -> single-dispatch scan -> scatter
// ---------------------------------------------------------------------------
__global__ __launch_bounds__(256) void k_hist(const int* __restrict__ tgt,
                                              int* __restrict__ deg) {
    int e = blockIdx.x * 256 + threadIdx.x;
    if (e < N_EDGES) atomicAdd(&deg[tgt[e]], 1);
}

__global__ __launch_bounds__(256) void k_scan_all(const int* __restrict__ deg,
                                                  int* __restrict__ off,
                                                  int* __restrict__ cursor) {
    __shared__ int ts[256];
    int tid = threadIdx.x;
    const int4* d4 = (const int4*)(deg + tid * 64);
    int s = 0;
    #pragma unroll
    for (int i = 0; i < 16; ++i) {
        int4 v = d4[i];
        s += v.x + v.y + v.z + v.w;
    }
    ts[tid] = s;
    __syncthreads();
    for (int o = 1; o < 256; o <<= 1) {
        int t = (tid >= o) ? ts[tid - o] : 0;
        __syncthreads();
        ts[tid] += t;
        __syncthreads();
    }
    int run = ts[tid] - s;
    int4* o4 = (int4*)(off + tid * 64);
    int4* c4 = (int4*)(cursor + tid * 64);
    #pragma unroll
    for (int i = 0; i < 16; ++i) {
        int4 v = d4[i];
        int4 ov;
        ov.x = run; run += v.x;
        ov.y = run; run += v.y;
        ov.z = run; run += v.z;
        ov.w = run; run += v.w;
        o4[i] = ov;
        c4[i] = ov;
    }
    if (tid == 255) off[N_NODES] = run;
}

__global__ __launch_bounds__(256) void k_scatter(const int* __restrict__ ei,
                                                 int* __restrict__ cursor,
                                                 int* __restrict__ csrc) {
    int e = blockIdx.x * 256 + threadIdx.x;
    if (e < N_EDGES) {
        int s = ei[e];
        int t = ei[N_EDGES + e];
        int pos = atomicAdd(&cursor[t], 1);
        csrc[pos] = s;
    }
}

// ---------------------------------------------------------------------------
// Layer 0 scores only (proj recomputed in registers)
// ---------------------------------------------------------------------------
__global__ __launch_bounds__(256) void k_l0s(const float* __restrict__ fea,
                                             const float* __restrict__ W0,
                                             const float* __restrict__ as,
                                             const float* __restrict__ at,
                                             float* __restrict__ ssrc,
                                             float* __restrict__ stgt) {
    int n = blockIdx.x, tid = threadIdx.x;
    float f0 = fea[n * 3 + 0], f1 = fea[n * 3 + 1], f2 = fea[n * 3 + 2];
    int c1 = tid, c2 = tid + 256;
    float p1 = f0 * W0[c1] + f1 * W0[512 + c1] + f2 * W0[1024 + c1];
    float p2 = f0 * W0[c2] + f1 * W0[512 + c2] + f2 * W0[1024 + c2];
    float vs1 = p1 * as[c1], vt1 = p1 * at[c1];
    float vs2 = p2 * as[c2], vt2 = p2 * at[c2];
    #pragma unroll
    for (int o = 32; o; o >>= 1) {
        vs1 += __shfl_xor(vs1, o); vt1 += __shfl_xor(vt1, o);
        vs2 += __shfl_xor(vs2, o); vt2 += __shfl_xor(vt2, o);
    }
    int lane = tid & 63, w = tid >> 6;
    if (lane == 0) {
        ssrc[n * 8 + w]     = vs1;  stgt[n * 8 + w]     = vt1;
        ssrc[n * 8 + w + 4] = vs2;  stgt[n * 8 + w + 4] = vt2;
    }
}

// ---------------------------------------------------------------------------
// Weight pack (both layers in one dispatch)
// ---------------------------------------------------------------------------
__device__ __forceinline__ void pack_slot(const float* __restrict__ src0,
                                          const float* __restrict__ src1,
                                          int splitN, int NTOT, int NKB, int s,
                                          unsigned short* __restrict__ hi,
                                          unsigned short* __restrict__ lo) {
    int nb = s / (NKB * 512);
    int rem = s - nb * (NKB * 512);
    int kb = rem >> 9;
    int sl = rem & 511;
    int c = sl >> 7, n = sl & 127;
    int col = nb * 128 + n;
    const float* src;
    int cc, stride;
    if (col < splitN) { src = src0; cc = col; stride = splitN; }
    else              { src = src1; cc = col - splitN; stride = NTOT - splitN; }
    int k0 = kb * 32 + c * 8;
    s16x8 hv, lv;
    #pragma unroll
    for (int j = 0; j < 8; ++j) {
        float w = src[(size_t)(k0 + j) * stride + cc];
        unsigned short h = f2bf(w);
        hv[j] = (short)h;
        lv[j] = (short)f2bf(w - bf2f(h));
    }
    *(s16x8*)(hi + (size_t)s * 8) = hv;
    *(s16x8*)(lo + (size_t)s * 8) = lv;
}

__global__ __launch_bounds__(256) void k_pack_all(
    const float* __restrict__ W1, const float* __restrict__ sk1,
    unsigned short* __restrict__ pw1h, unsigned short* __restrict__ pw1l,
    const float* __restrict__ W2, const float* __restrict__ sk2,
    unsigned short* __restrict__ pw2h, unsigned short* __restrict__ pw2l) {
    int s = blockIdx.x * 256 + threadIdx.x;
    if (s < 131072) {
        pack_slot(W1, sk1, 1024, 2048, 16, s, pw1h, pw1l);
    } else {
        int s2 = s - 131072;
        if (s2 < 16384) pack_slot(W2, sk2, 64, 128, 32, s2, pw2h, pw2l);
    }
}

// ---------------------------------------------------------------------------
// bf16x3-split MFMA GEMM (verified round-5 form).
// SWZ: XCD-aware bijective workgroup swizzle (KS==1 only) — each XCD gets
// a contiguous chunk of row-panels so A-tiles stay in one L2.
// ---------------------------------------------------------------------------
template <int F, int NTOT, int KS, bool SWZ>
__global__ __launch_bounds__(256, 2) void k_gemm_mfma(
    const unsigned short* __restrict__ Xhi, const unsigned short* __restrict__ Xlo,
    const unsigned short* __restrict__ Wph, const unsigned short* __restrict__ Wpl,
    float* __restrict__ out0, float* __restrict__ out1, int splitN) {
    constexpr int NKB = F / 32;
    static_assert(KS == 1 || NTOT == 128, "split-K assumes single col-block");
    __shared__ unsigned short lds[2 * 16384];
    const int tid = threadIdx.x;

    int bm, nb;
    if constexpr (SWZ && KS == 1) {
        constexpr int NB  = NTOT / 128;
        constexpr int TOT = (N_NODES / 128) * NB;
        constexpr int Q   = TOT / 8;                 // TOT % 8 == 0 (bijective)
        int wgid = blockIdx.y * NB + blockIdx.x;
        int swz  = (wgid & 7) * Q + (wgid >> 3);
        nb = swz % NB;
        bm = (swz / NB) * 128;
    } else {
        bm = blockIdx.y * 128;
        nb = blockIdx.x;
    }

    const int sA0 = tid, sA1 = tid + 256;
    const int rA0 = sA0 >> 2, rA1 = sA1 >> 2;
    const int cA0 = (sA0 & 3) ^ ((rA0 >> 1) & 3);
    const int cA1 = (sA1 & 3) ^ ((rA1 >> 1) & 3);
    const unsigned short* gAh0 = Xhi + (size_t)(bm + rA0) * F + cA0 * 8;
    const unsigned short* gAh1 = Xhi + (size_t)(bm + rA1) * F + cA1 * 8;
    const unsigned short* gAl0 = Xlo + (size_t)(bm + rA0) * F + cA0 * 8;
    const unsigned short* gAl1 = Xlo + (size_t)(bm + rA1) * F + cA1 * 8;
    const unsigned short* gBh  = Wph + (KS == 1 ? (size_t)nb * NKB * 4096 : 0);
    const unsigned short* gBl  = Wpl + (KS == 1 ? (size_t)nb * NKB * 4096 : 0);

    const int wave = tid >> 6, lane = tid & 63;
    const int wm = wave >> 1, wn = wave & 1;
    const int l15 = lane & 15, lc = lane >> 4;

    int offA[4], offB[4];
    #pragma unroll
    for (int mi = 0; mi < 4; ++mi) {
        int row = wm * 64 + mi * 16 + l15;
        int chp = lc ^ ((row >> 1) & 3);
        offA[mi] = row * 32 + chp * 8;
    }
    #pragma unroll
    for (int ni = 0; ni < 4; ++ni) {
        int n = wn * 64 + ni * 16 + l15;
        offB[ni] = 8192 + (lc * 128 + n) * 8;
    }

    f32x4 acc[4][4];
    #pragma unroll
    for (int i = 0; i < 4; ++i)
        #pragma unroll
        for (int j = 0; j < 4; ++j)
            acc[i][j] = (f32x4){0.f, 0.f, 0.f, 0.f};

    auto stage = [&](int kb, int buf) {
        unsigned short* l = &lds[buf * 16384];
        const size_t ka  = (size_t)kb * 32;
        const size_t kbb = (size_t)kb * 4096;
        GLL(gAh0 + ka, l + sA0 * 8);
        GLL(gAh1 + ka, l + sA1 * 8);
        GLL(gAl0 + ka, l + 4096 + sA0 * 8);
        GLL(gAl1 + ka, l + 4096 + sA1 * 8);
        GLL(gBh + kbb + sA0 * 8, l + 8192 + sA0 * 8);
        GLL(gBh + kbb + sA1 * 8, l + 8192 + sA1 * 8);
        GLL(gBl + kbb + sA0 * 8, l + 12288 + sA0 * 8);
        GLL(gBl + kbb + sA1 * 8, l + 12288 + sA1 * 8);
    };

    const int kb0 = (KS > 1) ? nb * (NKB / KS) : 0;
    const int kbN = (KS > 1) ? (NKB / KS) : NKB;

    stage(kb0, 0);
    __syncthreads();

    for (int ki = 0; ki < kbN; ++ki) {
        const int buf = ki & 1;
        if (ki + 1 < kbN) stage(kb0 + ki + 1, buf ^ 1);
        const unsigned short* l = &lds[buf * 16384];
        bf16x8 ah[4], al[4], bh[4], bl[4];
        #pragma unroll
        for (int mi = 0; mi < 4; ++mi) {
            ah[mi] = *(const bf16x8*)(l + offA[mi]);
            al[mi] = *(const bf16x8*)(l + 4096 + offA[mi]);
        }
        #pragma unroll
        for (int ni = 0; ni < 4; ++ni) {
            bh[ni] = *(const bf16x8*)(l + offB[ni]);
            bl[ni] = *(const bf16x8*)(l + 4096 + offB[ni]);
        }
        #pragma unroll
        for (int mi = 0; mi < 4; ++mi)
            #pragma unroll
            for (int ni = 0; ni < 4; ++ni) {
                acc[mi][ni] = __builtin_amdgcn_mfma_f32_16x16x32_bf16(ah[mi], bh[ni], acc[mi][ni], 0, 0, 0);
                acc[mi][ni] = __builtin_amdgcn_mfma_f32_16x16x32_bf16(ah[mi], bl[ni], acc[mi][ni], 0, 0, 0);
                acc[mi][ni] = __builtin_amdgcn_mfma_f32_16x16x32_bf16(al[mi], bh[ni], acc[mi][ni], 0, 0, 0);
            }
        __syncthreads();
    }

    if constexpr (KS > 1) {
        #pragma unroll
        for (int ni = 0; ni < 4; ++ni) {
            int col = wn * 64 + ni * 16 + l15;
            #pragma unroll
            for (int mi = 0; mi < 4; ++mi) {
                int row0 = bm + wm * 64 + mi * 16 + lc * 4;
                #pragma unroll
                for (int r = 0; r < 4; ++r)
                    out0[((size_t)nb * N_NODES + row0 + r) * NTOT + col] = acc[mi][ni][r];
            }
        }
    } else {
        #pragma unroll
        for (int ni = 0; ni < 4; ++ni) {
            int col = nb * 128 + wn * 64 + ni * 16 + l15;
            float* o;
            int cc, stride;
            if (col < splitN) { o = out0; cc = col; stride = splitN; }
            else              { o = out1; cc = col - splitN; stride = NTOT - splitN; }
            #pragma unroll
            for (int mi = 0; mi < 4; ++mi) {
                int row0 = bm + wm * 64 + mi * 16 + lc * 4;
                #pragma unroll
                for (int r = 0; r < 4; ++r)
                    o[(size_t)(row0 + r) * stride + cc] = acc[mi][ni][r];
            }
        }
    }
}

// ---------------------------------------------------------------------------
// Attention scores (layer 1) — P-based, fully coalesced.
// ---------------------------------------------------------------------------
template <int H, int FO>
__global__ __launch_bounds__(256) void k_scores(const float* __restrict__ P,
                                                const float* __restrict__ asrc,
                                                const float* __restrict__ atgt,
                                                float* __restrict__ ssrc,
                                                float* __restrict__ stgt) {
    constexpr int K = H * FO;
    int gid  = blockIdx.x * 4 + (threadIdx.x >> 6);
    int lane = threadIdx.x & 63;
    int n = gid / H, h = gid - n * H;
    if (n >= N_NODES) return;
    float vs = 0.f, vt = 0.f;
    #pragma unroll
    for (int q = 0; q < FO / 64; ++q) {
        int f = lane + q * 64;
        float p = P[(size_t)n * K + h * FO + f];
        vs += p * asrc[h * FO + f];
        vt += p * atgt[h * FO + f];
    }
    #pragma unroll
    for (int o = 32; o; o >>= 1) {
        vs += __shfl_xor(vs, o);
        vt += __shfl_xor(vt, o);
    }
    if (lane == 0) {
        ssrc[n * H + h] = vs;
        stgt[n * H + h] = vt;
    }
}

// ---------------------------------------------------------------------------
// Split-K reduce + layer-2 scores, fused. 16 nodes per block.
// ---------------------------------------------------------------------------
__global__ __launch_bounds__(256) void k_red2s(const float* __restrict__ part,
                                               const float* __restrict__ as2,
                                               const float* __restrict__ at2,
                                               float* __restrict__ P2,
                                               float* __restrict__ S2,
                                               float* __restrict__ ssrc,
                                               float* __restrict__ stgt) {
    int tid = threadIdx.x;
    int node = blockIdx.x * 16 + (tid >> 4);
    int cg = tid & 15;
    int c0 = cg * 8;
    const float* p0 = part + (size_t)node * 128 + c0;
    float v[8];
    {
        float4 a = *(const float4*)(p0);
        float4 b = *(const float4*)(p0 + 4);
        v[0]=a.x; v[1]=a.y; v[2]=a.z; v[3]=a.w; v[4]=b.x; v[5]=b.y; v[6]=b.z; v[7]=b.w;
    }
    #pragma unroll
    for (int ks = 1; ks < 4; ++ks) {
        const float* pk = p0 + (size_t)ks * N_NODES * 128;
        float4 a = *(const float4*)(pk);
        float4 b = *(const float4*)(pk + 4);
        v[0]+=a.x; v[1]+=a.y; v[2]+=a.z; v[3]+=a.w; v[4]+=b.x; v[5]+=b.y; v[6]+=b.z; v[7]+=b.w;
    }
    if (cg < 8) {
        float s = 0.f, t = 0.f;
        #pragma unroll
        for (int j = 0; j < 8; ++j) {
            s += v[j] * as2[c0 + j];
            t += v[j] * at2[c0 + j];
        }
        #pragma unroll
        for (int o = 1; o < 8; o <<= 1) { s += __shfl_xor(s, o); t += __shfl_xor(t, o); }
        float* d = P2 + (size_t)node * 64 + c0;
        *(float4*)(d)     = make_float4(v[0], v[1], v[2], v[3]);
        *(float4*)(d + 4) = make_float4(v[4], v[5], v[6], v[7]);
        if (cg == 0) { ssrc[node] = s; stgt[node] = t; }
    } else {
        float* d = S2 + (size_t)node * 64 + (c0 - 64);
        *(float4*)(d)     = make_float4(v[0], v[1], v[2], v[3]);
        *(float4*)(d + 4) = make_float4(v[4], v[5], v[6], v[7]);
    }
}

// ---------------------------------------------------------------------------
// Layer-0 fused attention, deg<=256 fast path, materialized alpha (r9 form).
// ---------------------------------------------------------------------------
__global__ __launch_bounds__(256) void k_attn0(
    const float* __restrict__ fea, const float* __restrict__ W0,
    const float* __restrict__ sk0, const float* __restrict__ ssrc,
    const float* __restrict__ stgt, const int* __restrict__ off,
    const int* __restrict__ csrc, const float* __restrict__ bias,
    unsigned short* __restrict__ ohi, unsigned short* __restrict__ olo) {
    constexpr int H = 8, K = 512;
    int n = blockIdx.x, tid = threadIdx.x;
    __shared__ float st[H], mh[H], dh[H];
    __shared__ int   srcs[256];
    __shared__ float sfea[256][3];
    __shared__ float av[256 * H];
    const int c0 = tid * 2, h0 = tid >> 5;

    float w00 = W0[c0],        w01 = W0[c0 + 1];
    float w10 = W0[512 + c0],  w11 = W0[512 + c0 + 1];
    float w20 = W0[1024 + c0], w21 = W0[1024 + c0 + 1];

    int d0 = off[n], deg = off[n + 1] - d0;
    if (tid < H) st[tid] = stgt[n * H + tid];
    __syncthreads();

    float a0 = 0.f, a1 = 0.f;

    if (deg <= 256) {
        int cnt = deg;
        if (tid < cnt) srcs[tid] = csrc[d0 + tid];
        __syncthreads();
        for (int idx = tid; idx < cnt * 3; idx += 256)
            sfea[idx / 3][idx % 3] = fea[srcs[idx / 3] * 3 + idx % 3];
        for (int idx = tid; idx < cnt * H; idx += 256) {
            int e = idx >> 3, h = idx & 7;
            float v = ssrc[srcs[e] * H + h] + st[h];
            av[idx] = (v >= 0.f) ? v : 0.2f * v;
        }
        __syncthreads();
        if (tid < H) {
            float m = -INFINITY;
            for (int e = 0; e < cnt; ++e) m = fmaxf(m, av[e * H + tid]);
            float s = 0.f;
            for (int e = 0; e < cnt; ++e) s += expf(av[e * H + tid] - m);
            mh[tid] = m;
            dh[tid] = 1.f / (s + 1e-16f);
        }
        __syncthreads();
        for (int idx = tid; idx < cnt * H; idx += 256) {
            int h = idx & 7;
            av[idx] = expf(av[idx] - mh[h]) * dh[h];
        }
        __syncthreads();
        for (int e = 0; e < cnt; ++e) {
            float al = av[e * H + h0];
            float f0 = sfea[e][0], f1 = sfea[e][1], f2 = sfea[e][2];
            a0 += (f0 * w00 + f1 * w10 + f2 * w20) * al;
            a1 += (f0 * w01 + f1 * w11 + f2 * w21) * al;
        }
    } else {
        if (tid < H) { mh[tid] = -INFINITY; dh[tid] = 0.f; }
        __syncthreads();
        for (int base = 0; base < deg; base += 256) {
            int cnt = min(256, deg - base);
            if (tid < cnt) srcs[tid] = csrc[d0 + base + tid];
            __syncthreads();
            for (int idx = tid; idx < cnt * H; idx += 256) {
                int e = idx >> 3, h = idx & 7;
                float v = ssrc[srcs[e] * H + h] + st[h];
                av[idx] = (v >= 0.f) ? v : 0.2f * v;
            }
            __syncthreads();
            if (tid < H) {
                float m = mh[tid], d = dh[tid];
                float cm = -INFINITY;
                for (int e = 0; e < cnt; ++e) cm = fmaxf(cm, av[e * H + tid]);
                float nm = fmaxf(m, cm);
                float s = 0.f;
                for (int e = 0; e < cnt; ++e) s += expf(av[e * H + tid] - nm);
                d = ((m == -INFINITY) ? 0.f : d * expf(m - nm)) + s;
                mh[tid] = nm;
                dh[tid] = d;
            }
            __syncthreads();
        }
        if (tid < H) dh[tid] = 1.f / (dh[tid] + 1e-16f);
        __syncthreads();
        for (int base = 0; base < deg; base += 256) {
            int cnt = min(256, deg - base);
            if (tid < cnt) srcs[tid] = csrc[d0 + base + tid];
            __syncthreads();
            for (int idx = tid; idx < cnt * 3; idx += 256)
                sfea[idx / 3][idx % 3] = fea[srcs[idx / 3] * 3 + idx % 3];
            for (int idx = tid; idx < cnt * H; idx += 256) {
                int e = idx >> 3, h = idx & 7;
                float v = ssrc[srcs[e] * H + h] + st[h];
                v = (v >= 0.f) ? v : 0.2f * v;
                av[idx] = expf(v - mh[h]) * dh[h];
            }
            __syncthreads();
            for (int e = 0; e < cnt; ++e) {
                float al = av[e * H + h0];
                float f0 = sfea[e][0], f1 = sfea[e][1], f2 = sfea[e][2];
                a0 += (f0 * w00 + f1 * w10 + f2 * w20) * al;
                a1 += (f0 * w01 + f1 * w11 + f2 * w21) * al;
            }
            __syncthreads();
        }
    }

    float f0 = fea[n * 3], f1 = fea[n * 3 + 1], f2 = fea[n * 3 + 2];
    float r0 = a0 + f0 * sk0[c0]     + f1 * sk0[512 + c0]     + f2 * sk0[1024 + c0]     + bias[c0];
    float r1 = a1 + f0 * sk0[c0 + 1] + f1 * sk0[512 + c0 + 1] + f2 * sk0[1024 + c0 + 1] + bias[c0 + 1];
    r0 = (r0 > 0.f) ? r0 : expm1f(r0);
    r1 = (r1 > 0.f) ? r1 : expm1f(r1);
    u16x2 hv, lv;
    unsigned short hb0 = f2bf(r0); hv[0] = hb0; lv[0] = f2bf(r0 - bf2f(hb0));
    unsigned short hb1 = f2bf(r1); hv[1] = hb1; lv[1] = f2bf(r1 - bf2f(hb1));
    *(u16x2*)(ohi + (size_t)n * K + c0) = hv;
    *(u16x2*)(olo + (size_t)n * K + c0) = lv;
}

// ---------------------------------------------------------------------------
// Generic fused attention, deg<=256 fast path, materialized alpha (r9 form).
// CAND: node from index array, compact output row = blockIdx.x.
// ---------------------------------------------------------------------------
template <int H, int FO, bool ACT, bool SPLIT, bool CAND>
__global__ __launch_bounds__(256) void k_attn_g(
    const float* __restrict__ P, const float* __restrict__ ssrc,
    const float* __restrict__ stgt, const int* __restrict__ off,
    const int* __restrict__ csrc, const float* __restrict__ bias,
    const float* __restrict__ skipin, float* __restrict__ outf,
    unsigned short* __restrict__ ohi, unsigned short* __restrict__ olo,
    const int* __restrict__ nidx) {
    constexpr int K   = H * FO;
    constexpr int VEC = (K / 256 >= 4) ? 4 : ((K / 256 >= 1) ? (K / 256) : 1);
    constexpr int NT  = K / VEC;
    int n = CAND ? nidx[blockIdx.x] : blockIdx.x;
    int orow = CAND ? blockIdx.x : n;
    int tid = threadIdx.x;
    __shared__ float st[H], mh[H], dh[H];
    __shared__ int   srcs[256];
    __shared__ float av[256 * H];

    const int c0 = (tid < NT ? tid : 0) * VEC;
    const int h0 = c0 / FO;
    const float* pc = P + c0;

    int d0 = off[n], deg = off[n + 1] - d0;
    if (tid < H) st[tid] = stgt[n * H + tid];
    __syncthreads();

    float acc[VEC];
    #pragma unroll
    for (int j = 0; j < VEC; ++j) acc[j] = 0.f;

    if (deg <= 256) {
        int cnt = deg;
        if (tid < cnt) srcs[tid] = csrc[d0 + tid];
        __syncthreads();
        for (int idx = tid; idx < cnt * H; idx += 256) {
            int e = idx / H, h = idx - (idx / H) * H;
            float v = ssrc[srcs[e] * H + h] + st[h];
            av[idx] = (v >= 0.f) ? v : 0.2f * v;
        }
        __syncthreads();
        if (tid < H) {
            float m = -INFINITY;
            for (int e = 0; e < cnt; ++e) m = fmaxf(m, av[e * H + tid]);
            float s = 0.f;
            for (int e = 0; e < cnt; ++e) s += expf(av[e * H + tid] - m);
            mh[tid] = m;
            dh[tid] = 1.f / (s + 1e-16f);
        }
        __syncthreads();
        for (int idx = tid; idx < cnt * H; idx += 256) {
            int h = idx - (idx / H) * H;
            av[idx] = expf(av[idx] - mh[h]) * dh[h];
        }
        __syncthreads();
        if (NT == 256 || tid < NT) {
            for (int e = 0; e < cnt; ++e) {
                float a = av[e * H + h0];
                if constexpr (VEC == 4) {
                    const float4 v = *(const float4*)(pc + (size_t)srcs[e] * K);
                    acc[0] += v.x * a; acc[1] += v.y * a;
                    acc[2] += v.z * a; acc[3] += v.w * a;
                } else {
                    acc[0] += pc[(size_t)srcs[e] * K] * a;
                }
            }
        }
    } else {
        if (tid < H) { mh[tid] = -INFINITY; dh[tid] = 0.f; }
        __syncthreads();
        for (int base = 0; base < deg; base += 256) {
            int cnt = min(256, deg - base);
            if (tid < cnt) srcs[tid] = csrc[d0 + base + tid];
            __syncthreads();
            for (int idx = tid; idx < cnt * H; idx += 256) {
                int e = idx / H, h = idx - (idx / H) * H;
                float v = ssrc[srcs[e] * H + h] + st[h];
                av[idx] = (v >= 0.f) ? v : 0.2f * v;
            }
            __syncthreads();
            if (tid < H) {
                float m = mh[tid], d = dh[tid];
                float cm = -INFINITY;
                for (int e = 0; e < cnt; ++e) cm = fmaxf(cm, av[e * H + tid]);
                float nm = fmaxf(m, cm);
                float s = 0.f;
                for (int e = 0; e < cnt; ++e) s += expf(av[e * H + tid] - nm);
                d = ((m == -INFINITY) ? 0.f : d * expf(m - nm)) + s;
                mh[tid] = nm;
                dh[tid] = d;
            }
            __syncthreads();
        }
        if (tid < H) dh[tid] = 1.f / (dh[tid] + 1e-16f);
        __syncthreads();
        for (int base = 0; base < deg; base += 256) {
            int cnt = min(256, deg - base);
            if (tid < cnt) srcs[tid] = csrc[d0 + base + tid];
            __syncthreads();
            for (int idx = tid; idx < cnt * H; idx += 256) {
                int e = idx / H, h = idx - (idx / H) * H;
                float v = ssrc[srcs[e] * H + h] + st[h];
                v = (v >= 0.f) ? v : 0.2f * v;
                av[idx] = expf(v - mh[h]) * dh[h];
            }
            __syncthreads();
            if (NT == 256 || tid < NT) {
                for (int e = 0; e < cnt; ++e) {
                    float a = av[e * H + h0];
                    if constexpr (VEC == 4) {
                        const float4 v = *(const float4*)(pc + (size_t)srcs[e] * K);
                        acc[0] += v.x * a; acc[1] += v.y * a;
                        acc[2] += v.z * a; acc[3] += v.w * a;
                    } else {
                        acc[0] += pc[(size_t)srcs[e] * K] * a;
                    }
                }
            }
            __syncthreads();
        }
    }

    if (NT == 256 || tid < NT) {
        float r[VEC];
        if constexpr (VEC == 4) {
            const float4 s4 = *(const float4*)(skipin + (size_t)n * K + c0);
            r[0] = acc[0] + s4.x; r[1] = acc[1] + s4.y;
            r[2] = acc[2] + s4.z; r[3] = acc[3] + s4.w;
        } else {
            r[0] = acc[0] + skipin[(size_t)n * K + c0];
        }
        #pragma unroll
        for (int j = 0; j < VEC; ++j) {
            r[j] += bias[c0 + j];
            if (ACT) r[j] = (r[j] > 0.f) ? r[j] : expm1f(r[j]);
        }
        if constexpr (SPLIT) {
            if constexpr (VEC == 4) {
                u16x4 hv, lv;
                #pragma unroll
                for (int j = 0; j < 4; ++j) {
                    unsigned short hb = f2bf(r[j]);
                    hv[j] = hb; lv[j] = f2bf(r[j] - bf2f(hb));
                }
                *(u16x4*)(ohi + (size_t)orow * K + c0) = hv;
                *(u16x4*)(olo + (size_t)orow * K + c0) = lv;
            } else {
                unsigned short hb = f2bf(r[0]);
                ohi[(size_t)orow * K + c0] = hb;
                olo[(size_t)orow * K + c0] = f2bf(r[0] - bf2f(hb));
            }
        } else {
            if constexpr (VEC == 4) {
                *(float4*)(outf + (size_t)orow * K + c0) =
                    make_float4(r[0], r[1], r[2], r[3]);
            } else {
                outf[(size_t)orow * K + c0] = r[0];
            }
        }
    }
}

// ---------------------------------------------------------------------------
// Batched candidate MLP head: 16 candidates per block.
// ---------------------------------------------------------------------------
__global__ __launch_bounds__(256) void k_mlp(const float* __restrict__ X3c,
                                             const int* __restrict__ cid,
                                             const float* __restrict__ W1,
                                             const float* __restrict__ b1,
                                             const float* __restrict__ W2,
                                             const float* __restrict__ b2,
                                             const float* __restrict__ W3,
                                             const float* __restrict__ b3,
                                             float* __restrict__ out) {
    __shared__ float cf[16][64];
    __shared__ float h1s[16][256];
    __shared__ float red[16][4];
    int tid = threadIdx.x;
    int cbase = blockIdx.x * 16;
    for (int i = tid; i < 16 * 64; i += 256)
        cf[i >> 6][i & 63] = X3c[(size_t)cbase * 64 + i];
    __syncthreads();
    float a[16];
    #pragma unroll
    for (int ci = 0; ci < 16; ++ci) a[ci] = b1[tid];
    for (int k = 0; k < 64; ++k) {
        float wv = W1[k * 256 + tid];
        #pragma unroll
        for (int ci = 0; ci < 16; ++ci) a[ci] += cf[ci][k] * wv;
    }
    #pragma unroll
    for (int ci = 0; ci < 16; ++ci) h1s[ci][tid] = tanhf(a[ci]);
    __syncthreads();
    #pragma unroll
    for (int ci = 0; ci < 16; ++ci) a[ci] = b2[tid];
    for (int k = 0; k < 256; ++k) {
        float wv = W2[k * 256 + tid];
        #pragma unroll
        for (int ci = 0; ci < 16; ++ci) a[ci] += h1s[ci][k] * wv;
    }
    float w3 = W3[tid];
    int lane = tid & 63, wv_ = tid >> 6;
    #pragma unroll
    for (int ci = 0; ci < 16; ++ci) {
        float v = tanhf(a[ci]) * w3;
        #pragma unroll
        for (int o = 32; o; o >>= 1) v += __shfl_xor(v, o);
        if (lane == 0) red[ci][wv_] = v;
    }
    __syncthreads();
    if (tid < 16) {
        int c = cbase + tid;
        out[c] = red[tid][0] + red[tid][1] + red[tid][2] + red[tid][3] + b3[0];
        out[N_CAND + c] = (float)cid[c];
    }
}

// ---------------------------------------------------------------------------
extern "C" void kernel_launch(void* const* d_in, const int* in_sizes, int n_in,
                              void* d_out, int out_size, void* d_ws, size_t ws_size,
                              hipStream_t stream) {
    const float* fea  = (const float*)d_in[0];
    const int*   ei   = (const int*)d_in[1];
    const int*   cid  = (const int*)d_in[2];
    const float* W0   = (const float*)d_in[3];
    const float* as0  = (const float*)d_in[4];
    const float* at0  = (const float*)d_in[5];
    const float* b0   = (const float*)d_in[6];
    const float* sk0  = (const float*)d_in[7];
    const float* W1   = (const float*)d_in[8];
    const float* as1  = (const float*)d_in[9];
    const float* at1  = (const float*)d_in[10];
    const float* b1   = (const float*)d_in[11];
    const float* sk1  = (const float*)d_in[12];
    const float* W2   = (const float*)d_in[13];
    const float* as2  = (const float*)d_in[14];
    const float* at2  = (const float*)d_in[15];
    const float* b2   = (const float*)d_in[16];
    const float* sk2  = (const float*)d_in[17];
    const float* mW1  = (const float*)d_in[18];
    const float* mb1  = (const float*)d_in[19];
    const float* mW2  = (const float*)d_in[20];
    const float* mb2  = (const float*)d_in[21];
    const float* mW3  = (const float*)d_in[22];
    const float* mb3  = (const float*)d_in[23];

    char* w = (char*)d_ws;
    auto alloc = [&](size_t bytes) -> void* {
        void* p = (void*)w;
        w += (bytes + 255) & ~(size_t)255;
        return p;
    };
    int*   deg    = (int*)alloc((size_t)N_NODES * 4);
    int*   off    = (int*)alloc((size_t)(N_NODES + 1) * 4);
    int*   cursor = (int*)alloc((size_t)N_NODES * 4);
    int*   csrc   = (int*)alloc((size_t)N_EDGES * 4);
    float* ssrc   = (float*)alloc((size_t)N_NODES * 8 * 4);
    float* stgt   = (float*)alloc((size_t)N_NODES * 8 * 4);
    float* P      = (float*)alloc((size_t)N_NODES * 1024 * 4);   // proj1 -> part
    float* S      = (float*)alloc((size_t)N_NODES * 1024 * 4);   // skip1 -> P2/S2/X3c
    unsigned short* Xs = (unsigned short*)alloc((size_t)N_NODES * 1024 * 4);
    unsigned short* pw1h = (unsigned short*)alloc((size_t)512 * 2048 * 2);
    unsigned short* pw1l = (unsigned short*)alloc((size_t)512 * 2048 * 2);
    unsigned short* pw2h = (unsigned short*)alloc((size_t)1024 * 128 * 2);
    unsigned short* pw2l = (unsigned short*)alloc((size_t)1024 * 128 * 2);

    unsigned short* X1hi = Xs;
    unsigned short* X1lo = Xs + (size_t)N_NODES * 512;
    unsigned short* X2hi = Xs;
    unsigned short* X2lo = Xs + (size_t)N_NODES * 1024;
    float* part = P;                                   // 4 x 16384 x 128 fp32
    float* P2   = S;                                   // proj2 (16384 x 64)
    float* S2   = S + (size_t)N_NODES * 64;            // skip2 (16384 x 64)
    float* X3c  = S + (size_t)2 * N_NODES * 64;        // compact cand out

    // CSR build
    hipMemsetAsync(deg, 0, (size_t)N_NODES * 4, stream);
    k_hist<<<N_EDGES / 256, 256, 0, stream>>>(ei + N_EDGES, deg);
    k_scan_all<<<1, 256, 0, stream>>>(deg, off, cursor);
    k_scatter<<<N_EDGES / 256, 256, 0, stream>>>(ei, cursor, csrc);

    // Weight packing (both layers, one dispatch)
    k_pack_all<<<576, 256, 0, stream>>>(W1, sk1, pw1h, pw1l, W2, sk2, pw2h, pw2l);

    // Layer 0
    k_l0s<<<N_NODES, 256, 0, stream>>>(fea, W0, as0, at0, ssrc, stgt);
    k_attn0<<<N_NODES, 256, 0, stream>>>(fea, W0, sk0, ssrc, stgt, off, csrc,
                                         b0, X1hi, X1lo);

    // Layer 1: fused proj+skip GEMM (N=2048, XCD-swizzled), P-based scores
    {
        dim3 g(16, N_NODES / 128);
        k_gemm_mfma<512, 2048, 1, true><<<g, 256, 0, stream>>>(
            X1hi, X1lo, pw1h, pw1l, P, S, 1024);
    }
    k_scores<8, 128><<<N_NODES * 8 / 4, 256, 0, stream>>>(P, as1, at1, ssrc, stgt);
    k_attn_g<8, 128, true, true, false><<<N_NODES, 256, 0, stream>>>(
        P, ssrc, stgt, off, csrc, b1, S, nullptr, X2hi, X2lo, nullptr);

    // Layer 2: split-K=4 GEMM -> fused reduce + scores -> candidate-only attn
    {
        dim3 g(4, N_NODES / 128);
        k_gemm_mfma<1024, 128, 4, false><<<g, 256, 0, stream>>>(
            X2hi, X2lo, pw2h, pw2l, part, nullptr, 128);
    }
    k_red2s<<<N_NODES / 16, 256, 0, stream>>>(part, as2, at2, P2, S2, ssrc, stgt);
    k_attn_g<1, 64, false, false, true><<<N_CAND, 256, 0, stream>>>(
        P2, ssrc, stgt, off, csrc, b2, S2, X3c, nullptr, nullptr, cid);

    // Batched candidate MLP head
    k_mlp<<<N_CAND / 16, 256, 0, stream>>>(X3c, cid, mW1, mb1, mW2, mb2, mW3, mb3,
                                           (float*)d_out);
}